// Round 3
// baseline (223.505 us; speedup 1.0000x reference)
//
#include <hip/hip_runtime.h>

// B=2, F=T=2048, HIDDEN=1024 (16 heads x 64)
// prep (cvt+transpose_w+mask_pack), gemm_qkv (z-fused, BK=64), attn_fused.
// Round 8: attn rebuilt on 32x32x16 MFMA. S^T 32x32 C-layout -> PV B-fragment
// via v_permlane32_swap (T12): P stays in registers, Ps LDS buffer deleted.
// Freed LDS double-buffers Ks/Vs (64 KB) -> ONE barrier/iter (16 total, was 32).
// l-sum = VALU sum of truncated P words (same rounding as numerator).
// K/V LDS rows 128 B, XOR swizzle col^=((row&7)<<3) on both write and read.
// Round 9 FIX: lanes l and l+32 share q (col=lane&31) but hold disjoint t-row
// halves (row += 4*(lane>>5)); the per-lane l-sum must be reduced across the
// lane-halves too -> one __shfl_xor(lsum, 32) before the epilogue combine.

typedef short v8s __attribute__((ext_vector_type(8)));
typedef float v4f __attribute__((ext_vector_type(4)));
typedef float v16f __attribute__((ext_vector_type(16)));
typedef unsigned int v2u __attribute__((ext_vector_type(2)));
typedef unsigned short u16;
typedef unsigned int   u32;
typedef unsigned long long u64;

constexpr float QSCALE = 0.18033688011112042f;  // 0.125 * log2(e)

__device__ __forceinline__ u16 f2bf(float f) {
    u32 u = __builtin_bit_cast(u32, f);
    u += 0x7fffu + ((u >> 16) & 1u);
    return (u16)(u >> 16);
}

// truncating bf16 pair pack: {b[31:16], a[31:16]} in ONE v_perm_b32
__device__ __forceinline__ u32 pack_trunc(float a, float b) {
    return __builtin_amdgcn_perm(__builtin_bit_cast(u32, b),
                                 __builtin_bit_cast(u32, a), 0x07060302u);
}

__device__ __forceinline__ v8s ld8(const u16* p) {
    return *reinterpret_cast<const v8s*>(p);
}

__device__ __forceinline__ void async16(const void* g, void* l) {
    __builtin_amdgcn_global_load_lds(
        (const __attribute__((address_space(1))) u32*)g,
        (__attribute__((address_space(3))) u32*)l, 16, 0, 0);
}

// ---------------- fused prep: cvt x2 | W transpose | mask pack ----------------
__global__ __launch_bounds__(256) void prep(
    const float* __restrict__ from, const float* __restrict__ to,
    u16* __restrict__ Xf, u16* __restrict__ Xt,
    const float* __restrict__ Wq, const float* __restrict__ Wk, const float* __restrict__ Wv,
    u16* __restrict__ Wqt, u16* __restrict__ Wkt, u16* __restrict__ Wvt,
    const int* __restrict__ mask, u64* __restrict__ words) {
    __shared__ float tile[32][33];
    const int bid = blockIdx.x, tid = threadIdx.x;
    if (bid < 8192) {
        int i = bid * 256 + tid;
        const float4* s;
        ushort4* d;
        int j;
        if (i < 1048576) { s = (const float4*)from; d = (ushort4*)Xf; j = i; }
        else             { s = (const float4*)to;   d = (ushort4*)Xt; j = i - 1048576; }
        float4 v = s[j];
        ushort4 o;
        o.x = f2bf(v.x); o.y = f2bf(v.y); o.z = f2bf(v.z); o.w = f2bf(v.w);
        d[j] = o;
    } else if (bid < 11264) {
        const int r = bid - 8192;
        const int zz = r >> 10, rem = r & 1023;
        const float* W = zz == 0 ? Wq : (zz == 1 ? Wk : Wv);
        u16* Wt = zz == 0 ? Wqt : (zz == 1 ? Wkt : Wvt);
        const int tx = tid & 31, ty = tid >> 5;
        const int n0 = (rem & 31) * 32, k0 = (rem >> 5) * 32;
        for (int i = 0; i < 4; i++)
            tile[ty + i * 8][tx] = W[(size_t)(k0 + ty + i * 8) * 1024 + n0 + tx];
        __syncthreads();
        for (int i = 0; i < 4; i++)
            Wt[(size_t)(n0 + ty + i * 8) * 1024 + k0 + tx] = f2bf(tile[tx][ty + i * 8]);
    } else {
        int g = (bid - 11264) * 256 + tid;
        int w = g >> 6, lane = g & 63;
        int v = mask[(size_t)w * 64 + lane];
        u64 bits = __ballot(v != 0);
        if (lane == 0) words[w] = bits;
    }
}

// ---------------- z-fused bf16 GEMM, BK=64: C[4096][1024] = A @ W^T + bias ----------------
__global__ __launch_bounds__(256) void gemm_qkv(
    const u16* __restrict__ Xf, const u16* __restrict__ Xt,
    const u16* __restrict__ Wqt, const u16* __restrict__ Wkt, const u16* __restrict__ Wvt,
    const float* __restrict__ bq, const float* __restrict__ bk, const float* __restrict__ bv,
    u16* __restrict__ Qb, u16* __restrict__ Kb, u16* __restrict__ Vtb) {
    const int z = blockIdx.z;
    const u16* A      = z == 0 ? Xf : Xt;
    const u16* Bt     = z == 0 ? Wqt : (z == 1 ? Wkt : Wvt);
    const float* bias = z == 0 ? bq : (z == 1 ? bk : bv);
    u16* C            = z == 0 ? Qb : (z == 1 ? Kb : Vtb);
    const int mode    = (z == 2);
    const float sc    = (z == 0) ? QSCALE : 1.0f;

    __shared__ u16 As[2][128][32];   // [khalf][row][32] 16 KB
    __shared__ u16 Bs[2][128][32];
    const uint4* Ag = reinterpret_cast<const uint4*>(A);
    const uint4* Bg = reinterpret_cast<const uint4*>(Bt);

    const int tid = threadIdx.x;
    const int lane = tid & 63, wave = tid >> 6;
    const int quad = lane >> 4, l16 = lane & 15;
    const int wm = wave >> 1, wn = wave & 1;
    const int m0 = blockIdx.x * 128, n0 = blockIdx.y * 128;

    const int cg  = (lane & 3) ^ ((lane >> 3) & 3);
    const int sw8 = (quad ^ ((l16 >> 1) & 3)) * 8;

    const int gi0 = wave * 4;
    const uint4 *ap0, *ap1, *ap2, *ap3, *bp0, *bp1, *bp2, *bp3;
    {
        const int rl = lane >> 2;
        const int rb0 = ((gi0 + 0) & 7) * 16 + rl, kh0 = (gi0 + 0) >> 3;
        const int rb1 = ((gi0 + 1) & 7) * 16 + rl, kh1 = (gi0 + 1) >> 3;
        const int rb2 = ((gi0 + 2) & 7) * 16 + rl, kh2 = (gi0 + 2) >> 3;
        const int rb3 = ((gi0 + 3) & 7) * 16 + rl, kh3 = (gi0 + 3) >> 3;
        ap0 = Ag + (size_t)(m0 + rb0) * 128 + kh0 * 4 + cg;
        ap1 = Ag + (size_t)(m0 + rb1) * 128 + kh1 * 4 + cg;
        ap2 = Ag + (size_t)(m0 + rb2) * 128 + kh2 * 4 + cg;
        ap3 = Ag + (size_t)(m0 + rb3) * 128 + kh3 * 4 + cg;
        bp0 = Bg + (size_t)(n0 + rb0) * 128 + kh0 * 4 + cg;
        bp1 = Bg + (size_t)(n0 + rb1) * 128 + kh1 * 4 + cg;
        bp2 = Bg + (size_t)(n0 + rb2) * 128 + kh2 * 4 + cg;
        bp3 = Bg + (size_t)(n0 + rb3) * 128 + kh3 * 4 + cg;
    }
    u16* Asl = (u16*)As + gi0 * 512;
    u16* Bsl = (u16*)Bs + gi0 * 512;

    v4f acc[4][4];
    for (int i = 0; i < 4; i++)
        for (int j = 0; j < 4; j++) acc[i][j] = (v4f)0.0f;

    for (int k0 = 0; k0 < 16; k0++) {
        __syncthreads();
        async16(ap0, Asl);        ap0 += 8;
        async16(ap1, Asl + 512);  ap1 += 8;
        async16(ap2, Asl + 1024); ap2 += 8;
        async16(ap3, Asl + 1536); ap3 += 8;
        async16(bp0, Bsl);        bp0 += 8;
        async16(bp1, Bsl + 512);  bp1 += 8;
        async16(bp2, Bsl + 1024); bp2 += 8;
        async16(bp3, Bsl + 1536); bp3 += 8;
        __syncthreads();

        #pragma unroll
        for (int kk = 0; kk < 2; kk++) {
            v8s af[4], bf[4];
            #pragma unroll
            for (int mt = 0; mt < 4; mt++) af[mt] = ld8(&As[kk][wm * 64 + mt * 16 + l16][sw8]);
            #pragma unroll
            for (int nt = 0; nt < 4; nt++) bf[nt] = ld8(&Bs[kk][wn * 64 + nt * 16 + l16][sw8]);
            #pragma unroll
            for (int mt = 0; mt < 4; mt++)
                #pragma unroll
                for (int nt = 0; nt < 4; nt++)
                    acc[mt][nt] = __builtin_amdgcn_mfma_f32_16x16x32_bf16(af[mt], bf[nt], acc[mt][nt], 0, 0, 0);
        }
    }

    #pragma unroll
    for (int nt = 0; nt < 4; nt++) {
        const int col = n0 + wn * 64 + nt * 16 + l16;
        const float bvv = bias[col];
        #pragma unroll
        for (int mt = 0; mt < 4; mt++) {
            const int mbase = m0 + wm * 64 + mt * 16 + quad * 4;
            if (mode == 0) {
                for (int r = 0; r < 4; r++)
                    C[(size_t)(mbase + r) * 1024 + col] = f2bf((acc[mt][nt][r] + bvv) * sc);
            } else {
                const int b = mbase >> 11, t = mbase & 2047;
                const int head = col >> 6, h = col & 63;
                ushort4 pk;
                pk.x = f2bf(acc[mt][nt][0] + bvv);
                pk.y = f2bf(acc[mt][nt][1] + bvv);
                pk.z = f2bf(acc[mt][nt][2] + bvv);
                pk.w = f2bf(acc[mt][nt][3] + bvv);
                *reinterpret_cast<ushort4*>(&C[(size_t)((b * 16 + head) * 64 + h) * 2048 + t]) = pk;
            }
        }
    }
}

// ---------------- fused flash attention, 32x32 MFMA, in-block t-split ----------------
// Q,K: bf16 [B][F/T][16][64] (Q pre-scaled); Vt: bf16 [B][16][64][2048]
// grid (32 bh, 16 f); block 512 = 8 waves. Wave w: q-rows (w&3)*32.., t-half w>>2.
// Per iter (64 t per t-half): S^T[64t][32q] via 2x4 mfma_32x32x16 (A=K, B=Q);
// exp+mask in-reg (C-layout col=q is lane-local); P packed to bf16 pairs and
// redistributed to the PV B-fragment with 8 v_permlane32_swap; O^T += V.P^T.
// LDS: [buf][K/V][128][64] double-buffered, one barrier/iter; K/V rows XOR-swizzled.
__global__ __launch_bounds__(512, 4) void attn_fused(
    const u16* __restrict__ Qb, const u16* __restrict__ Kb,
    const u16* __restrict__ Vtb, const u64* __restrict__ mw,
    float* __restrict__ out) {
    __shared__ u16 smem[2][2][128][64];   // [buf][K|V][row][col] 64 KB

    const int tid = threadIdx.x;
    const int lane = tid & 63, wave = tid >> 6;
    const int l32 = lane & 31, hL = lane >> 5;
    const int fwave = wave & 3, tw = wave >> 2;
    const int b = blockIdx.x >> 4, head = blockIdx.x & 15;
    const int f0 = blockIdx.y * 128;
    const int swz = (l32 & 7) << 3;       // u16 units, XOR on bits 3-5

    const uint4* Kg = reinterpret_cast<const uint4*>(Kb);
    const uint4* Vg = reinterpret_cast<const uint4*>(Vtb);
    const size_t vbase4 = (size_t)(b * 16 + head) * 64 * 256;

    // Q fragments (B-operand of 32x32x16): qf[kk] = Q[q=l32][kk*16 + hL*8 + e]
    v8s qf[4];
    {
        const u16* qp = Qb + ((size_t)(b * 2048 + f0 + fwave * 32 + l32) * 16 + head) * 64 + hL * 8;
        #pragma unroll
        for (int kk = 0; kk < 4; kk++) qf[kk] = ld8(qp + kk * 16);
    }

    // staging: 4 b128/wave/iter; waves 0-3 K rows, 4-7 V rows.
    // instr i covers 8 rows R = (wave&3)*32 + i*8 + (lane>>3) of [2 thalf][64].
    const uint4 *sp0, *sp1, *sp2, *sp3;
    size_t sinc;
    u16* sdl;   // per-lane LDS offset (buf term added per iter)
    {
        const int rl8 = lane >> 3, cl8 = lane & 7;
        sdl = (u16*)smem + (wave & 3) * 2048 + rl8 * 64 + ((cl8 ^ rl8) << 3)
            + ((wave >= 4) ? 8192 : 0);
        if (wave < 4) {
            sinc = 8192;   // +64 t rows * 16 heads * 8 uint4
            #define KR(i) (wave * 32 + (i) * 8 + rl8)
            #define KP(i) (Kg + ((size_t)(b * 2048 + (KR(i) >> 6) * 1024 + (KR(i) & 63)) * 16 + head) * 8 + cl8)
            sp0 = KP(0); sp1 = KP(1); sp2 = KP(2); sp3 = KP(3);
            #undef KP
            #undef KR
        } else {
            sinc = 8;      // +64 t along the Vt row
            #define VR(i) ((wave - 4) * 32 + (i) * 8 + rl8)
            #define VP(i) (Vg + vbase4 + (size_t)(VR(i) & 63) * 256 + (VR(i) >> 6) * 128 + cl8)
            sp0 = VP(0); sp1 = VP(1); sp2 = VP(2); sp3 = VP(3);
            #undef VP
            #undef VR
        }
    }

    v16f accO[2];
    accO[0] = (v16f)0.0f;
    accO[1] = (v16f)0.0f;
    float lsA = 0.0f, lsB = 0.0f;

    const u64* mrow = mw + (size_t)(b * 2048 + f0 + fwave * 32 + l32) * 32 + tw * 16;

    // prologue: tile 0 -> regs -> buf0; prefetch tile 1 into regs
    uint4 st0 = *sp0; sp0 += sinc;
    uint4 st1 = *sp1; sp1 += sinc;
    uint4 st2 = *sp2; sp2 += sinc;
    uint4 st3 = *sp3; sp3 += sinc;
    *reinterpret_cast<uint4*>(sdl)        = st0;
    *reinterpret_cast<uint4*>(sdl + 512)  = st1;
    *reinterpret_cast<uint4*>(sdl + 1024) = st2;
    *reinterpret_cast<uint4*>(sdl + 1536) = st3;
    st0 = *sp0; sp0 += sinc;
    st1 = *sp1; sp1 += sinc;
    st2 = *sp2; sp2 += sinc;
    st3 = *sp3; sp3 += sinc;
    __syncthreads();

    for (int it = 0; it < 16; it++) {
        const int buf = it & 1;
        const u64 mword = mrow[it];

        // write tile it+1 into buf^1 (vmcnt wait covers loads issued a full
        // iter ago); issue loads for tile it+2
        if (it < 15) {
            u16* sdst = sdl + (buf ^ 1) * 16384;
            *reinterpret_cast<uint4*>(sdst)        = st0;
            *reinterpret_cast<uint4*>(sdst + 512)  = st1;
            *reinterpret_cast<uint4*>(sdst + 1024) = st2;
            *reinterpret_cast<uint4*>(sdst + 1536) = st3;
            if (it < 14) {
                st0 = *sp0; sp0 += sinc;
                st1 = *sp1; sp1 += sinc;
                st2 = *sp2; sp2 += sinc;
                st3 = *sp3; sp3 += sinc;
            }
        }

        const u16* kvb = (const u16*)smem + buf * 16384;

        // QK^T + softmax, per 32-t block mt
        u32 pkw[2][8];
        #pragma unroll
        for (int mt = 0; mt < 2; mt++) {
            v16f s = (v16f)0.0f;
            #pragma unroll
            for (int kk = 0; kk < 4; kk++) {
                const v8s kf = *reinterpret_cast<const v8s*>(
                    kvb + (tw * 64 + mt * 32 + l32) * 64 + ((kk * 16 + hL * 8) ^ swz));
                s = __builtin_amdgcn_mfma_f32_32x32x16_bf16(kf, qf[kk], s, 0, 0, 0);
            }
            // lane holds S[t = mt*32 + (r&3)+8*(r>>2)+4*hL][q = l32]
            const u32 chunk = (u32)(mword >> (mt * 32 + hL * 4));
            #pragma unroll
            for (int wi = 0; wi < 8; wi++) {
                const int r0 = wi * 2;
                const int bp = (r0 & 3) + 8 * (r0 >> 2);
                const float e0 = __builtin_amdgcn_exp2f(s[r0]);
                const float e1 = __builtin_amdgcn_exp2f(s[r0 + 1]);
                const float p0 = ((chunk >> bp) & 1u) ? e0 : 0.0f;
                const float p1 = ((chunk >> (bp + 1)) & 1u) ? e1 : 0.0f;
                const u32 w = pack_trunc(p0, p1);
                pkw[mt][wi] = w;
                // l-sum over the SAME truncated values as the numerator
                lsA += __builtin_bit_cast(float, w << 16);
                lsB += __builtin_bit_cast(float, w & 0xffff0000u);
            }
        }

        // P redistribution (C-layout -> B-fragment) + PV, per 16-t chunk c
        #pragma unroll
        for (int c = 0; c < 4; c++) {
            const int mt = c >> 1, bse = (c & 1) * 4;
            u32 pbw[4];
            #pragma unroll
            for (int u = 0; u < 2; u++) {
                v2u rr = __builtin_amdgcn_permlane32_swap(
                    pkw[mt][bse + u], pkw[mt][bse + 2 + u], false, false);
                pbw[u]     = rr[0];
                pbw[u + 2] = rr[1];
            }
            uint4 pq;
            pq.x = pbw[0]; pq.y = pbw[1]; pq.z = pbw[2]; pq.w = pbw[3];
            const v8s pb = __builtin_bit_cast(v8s, pq);
            #pragma unroll
            for (int ht = 0; ht < 2; ht++) {
                const v8s vf = *reinterpret_cast<const v8s*>(
                    kvb + 8192 + (tw * 64 + ht * 32 + l32) * 64 + ((c * 16 + hL * 8) ^ swz));
                accO[ht] = __builtin_amdgcn_mfma_f32_32x32x16_bf16(vf, pb, accO[ht], 0, 0, 0);
            }
        }

        __syncthreads();
    }

    // ---- epilogue: combine the two t-halves in LDS (reuse smem) ----
    // l-sum: lanes l and l+32 hold disjoint t-row halves of the same q column
    // (C-layout row has the +4*(lane>>5) term) -> merge lane-halves first.
    const float lhalf = lsA + lsB;
    const float lsum = lhalf + __shfl_xor(lhalf, 32);

    float* fb = (float*)smem;   // 4 regions x 64 lanes x 36 floats = 36 KB
    if (tw == 1) {
        float* wdst = fb + fwave * 2304 + lane * 36;
        #pragma unroll
        for (int ht = 0; ht < 2; ht++)
            #pragma unroll
            for (int g = 0; g < 4; g++) {
                v4f t;
                t[0] = accO[ht][g * 4 + 0];
                t[1] = accO[ht][g * 4 + 1];
                t[2] = accO[ht][g * 4 + 2];
                t[3] = accO[ht][g * 4 + 3];
                *reinterpret_cast<v4f*>(wdst + ht * 16 + g * 4) = t;
            }
        wdst[32] = lsum;
    }
    __syncthreads();
    if (tw == 0) {
        const float* rsrc = fb + fwave * 2304 + lane * 36;
        const float inv = 1.0f / (lsum + rsrc[32]);
        const size_t ro = (size_t)(b * 2048 + f0 + fwave * 32 + l32) * 1024 + head * 64;
        #pragma unroll
        for (int ht = 0; ht < 2; ht++)
            #pragma unroll
            for (int g = 0; g < 4; g++) {
                const v4f p = *reinterpret_cast<const v4f*>(rsrc + ht * 16 + g * 4);
                float4 o;
                o.x = (accO[ht][g * 4 + 0] + p[0]) * inv;
                o.y = (accO[ht][g * 4 + 1] + p[1]) * inv;
                o.z = (accO[ht][g * 4 + 2] + p[2]) * inv;
                o.w = (accO[ht][g * 4 + 3] + p[3]) * inv;
                // h = ht*32 + 8g + 4hL + {0..3}
                *reinterpret_cast<float4*>(&out[ro + ht * 32 + g * 8 + hL * 4]) = o;
            }
    }
}

extern "C" void kernel_launch(void* const* d_in, const int* in_sizes, int n_in,
                              void* d_out, int out_size, void* d_ws, size_t ws_size,
                              hipStream_t stream) {
    const float* from = (const float*)d_in[0];
    const float* to   = (const float*)d_in[1];
    const int*   mask = (const int*)d_in[2];
    const float* Wq = (const float*)d_in[3];
    const float* bq = (const float*)d_in[4];
    const float* Wk = (const float*)d_in[5];
    const float* bk = (const float*)d_in[6];
    const float* Wv = (const float*)d_in[7];
    const float* bv = (const float*)d_in[8];
    float* out = (float*)d_out;

    u16* Xf  = (u16*)d_ws;            // 4096x1024 bf16
    u16* Xt  = Xf  + 4194304;
    u16* Wqt = Xt  + 4194304;         // 1024x1024 each
    u16* Wkt = Wqt + 1048576;
    u16* Wvt = Wkt + 1048576;
    u16* Qb  = Wvt + 1048576;         // 4096x1024
    u16* Kb  = Qb  + 4194304;
    u16* Vtb = Kb  + 4194304;         // [2][16][64][2048]
    u64* mwords = (u64*)(Vtb + 4194304);  // 2*2048*32 words

    prep<<<44032, 256, 0, stream>>>(from, to, Xf, Xt, Wq, Wk, Wv, Wqt, Wkt, Wvt, mask, mwords);

    gemm_qkv<<<dim3(32, 8, 3), 256, 0, stream>>>(Xf, Xt, Wqt, Wkt, Wvt, bq, bk, bv, Qb, Kb, Vtb);

    attn_fused<<<dim3(32, 16), 512, 0, stream>>>(Qb, Kb, Vtb, mwords, out);
}